// Round 11
// baseline (183.768 us; speedup 1.0000x reference)
//
#include <hip/hip_runtime.h>
#include <float.h>

#define NPTS 8192
#define MPTS 8192
#define FDIM 256

#define BM 128
#define BN 128
#define BK 32
#define TCT (MPTS / BN)   /* 64 column tiles */
#define TRT (NPTS / BM)   /* 64 row tiles */

typedef unsigned short ushort_t;
typedef unsigned int u32;
typedef __attribute__((ext_vector_type(8))) short short8;
typedef __attribute__((ext_vector_type(4))) float floatx4;

// ---- top-2-by-similarity (proven round 8): select on RAW s (max); clamp and
// sqrt applied only at the ratio test. Any orderings-could-differ case forces
// d1==d2 -> ratio==1 -> ok=false under RT=1.0 -> decisions unaffected.
struct T2 { float s1, s2; int i1; };   // s1 >= s2

__device__ __forceinline__ T2 t2_sent() { T2 a; a.s1 = -FLT_MAX; a.s2 = -FLT_MAX; a.i1 = 0; return a; }

__device__ __forceinline__ T2 t2_merge(T2 a, T2 b) {
    T2 r;
    r.s1 = fmaxf(a.s1, b.s1);
    r.i1 = (b.s1 > a.s1) ? b.i1 : a.i1;
    r.s2 = fmaxf(fminf(a.s1, b.s1), fmaxf(a.s2, b.s2));
    return r;
}
__device__ __forceinline__ T2 t2_make4(float v0, float v1, float v2, float v3,
                                       int i0, int i1_, int i2, int i3) {
    float lo01 = fminf(v0, v1), hi01 = fmaxf(v0, v1);
    float lo23 = fminf(v2, v3), hi23 = fmaxf(v2, v3);
    int a01 = (v1 > v0) ? i1_ : i0;
    int a23 = (v3 > v2) ? i3 : i2;
    T2 r;
    r.s1 = fmaxf(hi01, hi23);
    r.i1 = (hi23 > hi01) ? a23 : a01;
    r.s2 = fmaxf(fminf(hi01, hi23), fmaxf(lo01, lo23));
    return r;
}
__device__ __forceinline__ float4 t2_pack(T2 a) {
    return make_float4(a.s1, a.s2, __int_as_float(a.i1), 0.0f);
}
__device__ __forceinline__ T2 t2_unpack(float4 v) {
    T2 a; a.s1 = v.x; a.s2 = v.y; a.i1 = __float_as_int(v.z); return a;
}
__device__ __forceinline__ T2 t2_shfl_xor(T2 a, int m) {
    T2 r; r.s1 = __shfl_xor(a.s1, m); r.s2 = __shfl_xor(a.s2, m); r.i1 = __shfl_xor(a.i1, m);
    return r;
}

__device__ __forceinline__ float bf2f(ushort_t u) {
    union { u32 i; float f; } v; v.i = ((u32)u) << 16; return v.f;
}
__device__ __forceinline__ ushort_t f2bf_rtne(float x) {
    u32 u = __float_as_uint(x);
    u32 r = u + 0x7FFFu + ((u >> 16) & 1u);
    return (ushort_t)(r >> 16);
}

// -------- fused transpose + hi/lo split for BOTH matrices (proven) --------
__global__ __launch_bounds__(256) void transpose_split(
    const float* __restrict__ s0, const float* __restrict__ s1,
    ushort_t* __restrict__ hi0, ushort_t* __restrict__ lo0,
    ushort_t* __restrict__ hi1, ushort_t* __restrict__ lo1)
{
    __shared__ ushort_t hiS[64][66];
    __shared__ ushort_t loS[64][66];
    const float* src = blockIdx.z ? s1 : s0;
    ushort_t* hiT = blockIdx.z ? hi1 : hi0;
    ushort_t* loT = blockIdx.z ? lo1 : lo0;
    const int t = threadIdx.x;
    const int n0 = blockIdx.x * 64, f0 = blockIdx.y * 64;
#pragma unroll
    for (int p = 0; p < 16; p++) {
        int fl = (t >> 6) + p * 4;
        int nl = t & 63;
        float x = src[(size_t)(f0 + fl) * NPTS + n0 + nl];
        ushort_t hb = f2bf_rtne(x);
        ushort_t lb = f2bf_rtne(x - bf2f(hb));
        hiS[nl][fl] = hb;
        loS[nl][fl] = lb;
    }
    __syncthreads();
#pragma unroll
    for (int p = 0; p < 8; p++) {
        int nl = (t >> 5) + p * 8;
        int fp = (t & 31) * 2;
        u32 hw = (u32)hiS[nl][fp] | ((u32)hiS[nl][fp + 1] << 16);
        u32 lw = (u32)loS[nl][fp] | ((u32)loS[nl][fp + 1] << 16);
        size_t o = (size_t)(n0 + nl) * FDIM + f0 + fp;
        *(u32*)&hiT[o] = hw;
        *(u32*)&loT[o] = lw;
    }
}

#define GLDS(g, l) __builtin_amdgcn_global_load_lds( \
    (const __attribute__((address_space(1))) void*)(g), \
    (__attribute__((address_space(3))) void*)(l), 16, 0, 0)

// -------- fused MFMA GEMM (16x16x32) + f32 top-2 --------
// launch_bounds (256,3): natural allocation is 80 VGPR + 64 AGPR = 144 unified
// regs <= 168 (512-reg SIMD pool / 3 waves), so 3 blocks/CU without spill;
// third co-resident block de-phases barriers -> MFMA/VALU overlap.
__global__ __launch_bounds__(256, 3) void gemm_top2(
    const ushort_t* __restrict__ hiA, const ushort_t* __restrict__ loA,
    const ushort_t* __restrict__ hiB, const ushort_t* __restrict__ loB,
    float4* __restrict__ rowPart, float4* __restrict__ colPart)
{
    __shared__ char smem[36864];
    ushort_t* Ah = (ushort_t*)smem;                 // 8 KB each (staging)
    ushort_t* Bh = (ushort_t*)(smem + 8192);
    ushort_t* Al = (ushort_t*)(smem + 16384);
    ushort_t* Bl = (ushort_t*)(smem + 24576);
    // epilogue aliases (all uses strictly after staging is done + barrier):
    float* scrS1 = (float*)smem;                    // 64*33*4 = 8448 B
    float* scrS2 = (float*)(smem + 8448);
    int*   scrI  = (int*)(smem + 16896);            // ends 25344
    float4* redC = (float4*)(smem + 25600);         // 128*2*16 = 4096 B

    const int t = threadIdx.x;
    const int lane = t & 63, lc = lane & 15, q = lane >> 4;
    const int w = t >> 6, wx = w & 1, wy = w >> 1;
    const int ctile = blockIdx.x, rtile = blockIdx.y;
    const int n0 = rtile * BM, m0 = ctile * BN;

    floatx4 acc[4][4];
#pragma unroll
    for (int i = 0; i < 4; i++)
#pragma unroll
        for (int j = 0; j < 4; j++) acc[i][j] = (floatx4)0.0f;

    // staging (proven round 7): chunk swizzle pos = chunk ^ ((row>>1)&3)
    const int srow = t >> 2;
    const int skoff = (((t & 3) ^ ((t >> 3) & 3))) * 8;
    const size_t sldsOff = (size_t)t * 8;
    const int fkoff = (q ^ ((lc >> 1) & 3)) * 8;

    // hoisted staging base pointers; k0 advances via small adds
    const ushort_t* pAh0 = hiA + (size_t)(n0 + srow) * FDIM + skoff;
    const ushort_t* pAh1 = hiA + (size_t)(n0 + srow + 64) * FDIM + skoff;
    const ushort_t* pBh0 = hiB + (size_t)(m0 + srow) * FDIM + skoff;
    const ushort_t* pBh1 = hiB + (size_t)(m0 + srow + 64) * FDIM + skoff;
    const ushort_t* pAl0 = loA + (size_t)(n0 + srow) * FDIM + skoff;
    const ushort_t* pAl1 = loA + (size_t)(n0 + srow + 64) * FDIM + skoff;
    const ushort_t* pBl0 = loB + (size_t)(m0 + srow) * FDIM + skoff;
    const ushort_t* pBl1 = loB + (size_t)(m0 + srow + 64) * FDIM + skoff;

    for (int k0 = 0; k0 < FDIM; k0 += BK) {
        if (k0) __syncthreads();
        GLDS(pAh0 + k0, Ah + sldsOff);
        GLDS(pAh1 + k0, Ah + 2048 + sldsOff);
        GLDS(pBh0 + k0, Bh + sldsOff);
        GLDS(pBh1 + k0, Bh + 2048 + sldsOff);
        GLDS(pAl0 + k0, Al + sldsOff);
        GLDS(pAl1 + k0, Al + 2048 + sldsOff);
        GLDS(pBl0 + k0, Bl + sldsOff);
        GLDS(pBl1 + k0, Bl + 2048 + sldsOff);
        __syncthreads();

        short8 ah[4], bh[4], al[4], bl[4];
#pragma unroll
        for (int i = 0; i < 4; i++) {
            int r = (wy * 64 + i * 16 + lc) * BK;
            ah[i] = *(const short8*)&Ah[r + fkoff];
            al[i] = *(const short8*)&Al[r + fkoff];
        }
#pragma unroll
        for (int j = 0; j < 4; j++) {
            int r = (wx * 64 + j * 16 + lc) * BK;
            bh[j] = *(const short8*)&Bh[r + fkoff];
            bl[j] = *(const short8*)&Bl[r + fkoff];
        }
#pragma unroll
        for (int i = 0; i < 4; i++)
#pragma unroll
            for (int j = 0; j < 4; j++) {
                acc[i][j] = __builtin_amdgcn_mfma_f32_16x16x32_bf16(ah[i], bh[j], acc[i][j], 0, 0, 0);
                acc[i][j] = __builtin_amdgcn_mfma_f32_16x16x32_bf16(ah[i], bl[j], acc[i][j], 0, 0, 0);
                acc[i][j] = __builtin_amdgcn_mfma_f32_16x16x32_bf16(al[i], bh[j], acc[i][j], 0, 0, 0);
            }
    }

    // ---- epilogue: C/D layout row = q*4+reg, col = lane&15 (verified) ----
    T2 colT[4];
#pragma unroll
    for (int j = 0; j < 4; j++) colT[j] = t2_sent();
    T2 rowT[4][4];

    const int cb = m0 + wx * 64 + lc;
#pragma unroll
    for (int i = 0; i < 4; i++) {
#pragma unroll
        for (int r = 0; r < 4; r++)
            rowT[i][r] = t2_make4(acc[i][0][r], acc[i][1][r], acc[i][2][r], acc[i][3][r],
                                  cb, cb + 16, cb + 32, cb + 48);
        const int rb = n0 + wy * 64 + i * 16 + q * 4;
#pragma unroll
        for (int j = 0; j < 4; j++)
            colT[j] = t2_merge(colT[j],
                t2_make4(acc[i][j][0], acc[i][j][1], acc[i][j][2], acc[i][j][3],
                         rb, rb + 1, rb + 2, rb + 3));
    }

    // cols: merge across the 4 quads (same column, different row-quarters)
#pragma unroll
    for (int j = 0; j < 4; j++) {
        colT[j] = t2_merge(colT[j], t2_shfl_xor(colT[j], 16));
        colT[j] = t2_merge(colT[j], t2_shfl_xor(colT[j], 32));
        if (q == 0) redC[(wx * 64 + j * 16 + lc) * 2 + wy] = t2_pack(colT[j]);
    }

    // rows: two LDS rounds (by wy), bank-spread slots, free 2-way access
#pragma unroll
    for (int round = 0; round < 2; round++) {
        __syncthreads();
        if (wy == round) {
#pragma unroll
            for (int i = 0; i < 4; i++)
#pragma unroll
                for (int r = 0; r < 4; r++) {
                    int row = i * 16 + q * 4 + r;                 // 0..63
                    int col = (lc << 1) | wx;                     // 0..31
                    int slot = row * 33 + ((col + row + 9 * q) & 31);
                    scrS1[slot] = rowT[i][r].s1;
                    scrS2[slot] = rowT[i][r].s2;
                    scrI[slot]  = rowT[i][r].i1;
                }
        }
        __syncthreads();
        {
            int row = t >> 2, chunk = t & 3;
            T2 a = t2_sent();
#pragma unroll
            for (int s = 0; s < 8; s++) {
                int slot = row * 33 + ((chunk << 3) | s);
                T2 b; b.s1 = scrS1[slot]; b.s2 = scrS2[slot]; b.i1 = scrI[slot];
                a = t2_merge(a, b);
            }
            a = t2_merge(a, t2_shfl_xor(a, 1));
            a = t2_merge(a, t2_shfl_xor(a, 2));
            if (chunk == 0)
                rowPart[(size_t)ctile * NPTS + n0 + round * 64 + row] = t2_pack(a);
        }
    }

    __syncthreads();
    if (t < 128) {
        T2 m = t2_unpack(redC[t * 2 + 0]);
        m = t2_merge(m, t2_unpack(redC[t * 2 + 1]));
        colPart[(size_t)rtile * MPTS + m0 + t] = t2_pack(m);
    }
}

// -------- fused final reduce: forward top-2, then backward top-2 only for
// each row's fwd column (recomputed from colPart; L2-resident) --------
__global__ __launch_bounds__(256) void reduce_final(
    const float4* __restrict__ rowPart, const float4* __restrict__ colPart,
    float* __restrict__ out)
{
    __shared__ float4 sh[4][64];
    __shared__ int shFwd[64];
    __shared__ int shOk[64];
    const int t = threadIdx.x, nl = t & 63, sub = t >> 6;
    const int n = blockIdx.x * 64 + nl;

    T2 a = t2_sent();
#pragma unroll
    for (int k = 0; k < 16; k++)
        a = t2_merge(a, t2_unpack(rowPart[(size_t)(sub * 16 + k) * NPTS + n]));
    sh[sub][nl] = t2_pack(a);
    __syncthreads();
    if (t < 64) {
        T2 r = t2_unpack(sh[0][t]);
        r = t2_merge(r, t2_unpack(sh[1][t]));
        r = t2_merge(r, t2_unpack(sh[2][t]));
        r = t2_merge(r, t2_unpack(sh[3][t]));
        float c1 = fmaxf(1.0f - r.s1, 1e-6f), c2 = fmaxf(1.0f - r.s2, 1e-6f);
        float d1 = 1.414213f * sqrtf(c1), d2 = 1.414213f * sqrtf(c2);
        shFwd[t] = r.i1;
        shOk[t]  = ((d1 / d2) < 1.0f) ? 1 : 0;   // exact ref ratio test, RT=1.0
    }
    __syncthreads();
    const int fw = shFwd[nl];
    T2 c = t2_sent();
#pragma unroll
    for (int k = 0; k < 16; k++)
        c = t2_merge(c, t2_unpack(colPart[(size_t)(sub * 16 + k) * MPTS + fw]));
    sh[sub][nl] = t2_pack(c);
    __syncthreads();
    if (t < 64) {
        T2 r = t2_unpack(sh[0][t]);
        r = t2_merge(r, t2_unpack(sh[1][t]));
        r = t2_merge(r, t2_unpack(sh[2][t]));
        r = t2_merge(r, t2_unpack(sh[3][t]));
        float c1 = fmaxf(1.0f - r.s1, 1e-6f), c2 = fmaxf(1.0f - r.s2, 1e-6f);
        float d1 = 1.414213f * sqrtf(c1), d2 = 1.414213f * sqrtf(c2);
        bool bok = (d1 / d2) < 1.0f;
        int nn = blockIdx.x * 64 + t;
        bool mutual = (shOk[t] != 0) && bok && (r.i1 == nn);
        int idx0 = mutual ? shFwd[t] : -1;
        out[nn]             = (float)idx0;                // indices0
        out[NPTS + nn]      = -1.0f;                      // matches1 (all -1)
        out[2 * NPTS + nn]  = (idx0 > 0) ? 1.0f : 0.0f;   // mscores0 (strict >0 ref quirk)
        out[3 * NPTS + nn]  = 0.0f;                       // mscores1
    }
}

extern "C" void kernel_launch(void* const* d_in, const int* in_sizes, int n_in,
                              void* d_out, int out_size, void* d_ws, size_t ws_size,
                              hipStream_t stream)
{
    const float* d0 = (const float*)d_in[0];   // [1, 256, 8192] f32
    const float* d1 = (const float*)d_in[1];   // [1, 256, 8192] f32

    char* ws = (char*)d_ws;
    const size_t matB = (size_t)NPTS * FDIM * sizeof(ushort_t);      // 4 MB
    ushort_t* hiA = (ushort_t*)(ws);
    ushort_t* loA = (ushort_t*)(ws + matB);
    ushort_t* hiB = (ushort_t*)(ws + 2 * matB);
    ushort_t* loB = (ushort_t*)(ws + 3 * matB);
    char* p = ws + 4 * matB;
    const size_t rowBytes = (size_t)TCT * NPTS * sizeof(float4);     // 8 MB
    float4* rowPart = (float4*)p;
    float4* colPart = (float4*)(p + rowBytes);

    dim3 gt(NPTS / 64, FDIM / 64, 2);
    transpose_split<<<gt, 256, 0, stream>>>(d0, d1, hiA, loA, hiB, loB);

    dim3 g1(TCT, TRT);
    gemm_top2<<<g1, 256, 0, stream>>>(hiA, loA, hiB, loB, rowPart, colPart);
    reduce_final<<<NPTS / 64, 256, 0, stream>>>(rowPart, colPart, (float*)d_out);
}

// Round 12
// 181.511 us; speedup vs baseline: 1.0124x; 1.0124x over previous
//
#include <hip/hip_runtime.h>
#include <float.h>

#define NPTS 8192
#define MPTS 8192
#define FDIM 256

#define BM 128
#define BN 128
#define BK 32
#define TCT (MPTS / BN)   /* 64 column tiles */
#define TRT (NPTS / BM)   /* 64 row tiles */

typedef unsigned short ushort_t;
typedef unsigned int u32;
typedef __attribute__((ext_vector_type(8))) short short8;
typedef __attribute__((ext_vector_type(4))) float floatx4;
typedef __attribute__((ext_vector_type(4))) unsigned short ushort4v;

// ---- top-2-by-similarity (proven round 8): select on RAW s (max); clamp and
// sqrt applied only at the ratio test. Any orderings-could-differ case forces
// d1==d2 -> ratio==1 -> ok=false under RT=1.0 -> decisions unaffected.
struct T2 { float s1, s2; int i1; };   // s1 >= s2

__device__ __forceinline__ T2 t2_sent() { T2 a; a.s1 = -FLT_MAX; a.s2 = -FLT_MAX; a.i1 = 0; return a; }

__device__ __forceinline__ T2 t2_merge(T2 a, T2 b) {
    T2 r;
    r.s1 = fmaxf(a.s1, b.s1);
    r.i1 = (b.s1 > a.s1) ? b.i1 : a.i1;
    r.s2 = fmaxf(fminf(a.s1, b.s1), fmaxf(a.s2, b.s2));
    return r;
}
__device__ __forceinline__ T2 t2_make4(float v0, float v1, float v2, float v3,
                                       int i0, int i1_, int i2, int i3) {
    float lo01 = fminf(v0, v1), hi01 = fmaxf(v0, v1);
    float lo23 = fminf(v2, v3), hi23 = fmaxf(v2, v3);
    int a01 = (v1 > v0) ? i1_ : i0;
    int a23 = (v3 > v2) ? i3 : i2;
    T2 r;
    r.s1 = fmaxf(hi01, hi23);
    r.i1 = (hi23 > hi01) ? a23 : a01;
    r.s2 = fmaxf(fminf(hi01, hi23), fmaxf(lo01, lo23));
    return r;
}
__device__ __forceinline__ float4 t2_pack(T2 a) {
    return make_float4(a.s1, a.s2, __int_as_float(a.i1), 0.0f);
}
__device__ __forceinline__ T2 t2_unpack(float4 v) {
    T2 a; a.s1 = v.x; a.s2 = v.y; a.i1 = __float_as_int(v.z); return a;
}
__device__ __forceinline__ T2 t2_shfl_xor(T2 a, int m) {
    T2 r; r.s1 = __shfl_xor(a.s1, m); r.s2 = __shfl_xor(a.s2, m); r.i1 = __shfl_xor(a.i1, m);
    return r;
}

__device__ __forceinline__ float bf2f(ushort_t u) {
    union { u32 i; float f; } v; v.i = ((u32)u) << 16; return v.f;
}
__device__ __forceinline__ ushort_t f2bf_rtne(float x) {
    u32 u = __float_as_uint(x);
    u32 r = u + 0x7FFFu + ((u >> 16) & 1u);
    return (ushort_t)(r >> 16);
}

// -------- fused transpose + hi/lo split, fully vectorized --------
// Loads float4 (16 B/lane), LDS [64][72] (144 B rows: 8 B-aligned, 4-bank
// skew per row -> <=2-way conflicts), stores ushort4 (8 B/lane, dwordx2).
// Split math bit-identical to the proven scalar version.
__global__ __launch_bounds__(256) void transpose_split(
    const float* __restrict__ s0, const float* __restrict__ s1,
    ushort_t* __restrict__ hi0, ushort_t* __restrict__ lo0,
    ushort_t* __restrict__ hi1, ushort_t* __restrict__ lo1)
{
    __shared__ ushort_t hiS[64][72];
    __shared__ ushort_t loS[64][72];
    const float* src = blockIdx.z ? s1 : s0;
    ushort_t* hiT = blockIdx.z ? hi1 : hi0;
    ushort_t* loT = blockIdx.z ? lo1 : lo0;
    const int t = threadIdx.x;
    const int n0 = blockIdx.x * 64, f0 = blockIdx.y * 64;

#pragma unroll
    for (int p = 0; p < 4; p++) {
        int fl = (t >> 4) + p * 16;          // feature row 0..63
        int nl = (t & 15) * 4;               // 4 consecutive points
        float4 x = *(const float4*)&src[(size_t)(f0 + fl) * NPTS + n0 + nl];
        float xs[4] = {x.x, x.y, x.z, x.w};
#pragma unroll
        for (int e = 0; e < 4; e++) {
            ushort_t hb = f2bf_rtne(xs[e]);
            ushort_t lb = f2bf_rtne(xs[e] - bf2f(hb));
            hiS[nl + e][fl] = hb;
            loS[nl + e][fl] = lb;
        }
    }
    __syncthreads();
#pragma unroll
    for (int p = 0; p < 4; p++) {
        int nl = (t >> 4) + p * 16;          // point row 0..63
        int fp = (t & 15) * 4;               // 4 consecutive features
        ushort4v hv = *(const ushort4v*)&hiS[nl][fp];
        ushort4v lv = *(const ushort4v*)&loS[nl][fp];
        size_t o = (size_t)(n0 + nl) * FDIM + f0 + fp;
        *(ushort4v*)&hiT[o] = hv;
        *(ushort4v*)&loT[o] = lv;
    }
}

#define GLDS(g, l) __builtin_amdgcn_global_load_lds( \
    (const __attribute__((address_space(1))) void*)(g), \
    (__attribute__((address_space(3))) void*)(l), 16, 0, 0)

// -------- fused MFMA GEMM (16x16x32) + f32 top-2 (round-11 proven) --------
__global__ __launch_bounds__(256, 3) void gemm_top2(
    const ushort_t* __restrict__ hiA, const ushort_t* __restrict__ loA,
    const ushort_t* __restrict__ hiB, const ushort_t* __restrict__ loB,
    float4* __restrict__ rowPart, float4* __restrict__ colPart)
{
    __shared__ char smem[36864];
    ushort_t* Ah = (ushort_t*)smem;                 // 8 KB each (staging)
    ushort_t* Bh = (ushort_t*)(smem + 8192);
    ushort_t* Al = (ushort_t*)(smem + 16384);
    ushort_t* Bl = (ushort_t*)(smem + 24576);
    // epilogue aliases (all uses strictly after staging is done + barrier):
    float* scrS1 = (float*)smem;                    // 64*33*4 = 8448 B
    float* scrS2 = (float*)(smem + 8448);
    int*   scrI  = (int*)(smem + 16896);            // ends 25344
    float4* redC = (float4*)(smem + 25600);         // 128*2*16 = 4096 B

    const int t = threadIdx.x;
    const int lane = t & 63, lc = lane & 15, q = lane >> 4;
    const int w = t >> 6, wx = w & 1, wy = w >> 1;
    const int ctile = blockIdx.x, rtile = blockIdx.y;
    const int n0 = rtile * BM, m0 = ctile * BN;

    floatx4 acc[4][4];
#pragma unroll
    for (int i = 0; i < 4; i++)
#pragma unroll
        for (int j = 0; j < 4; j++) acc[i][j] = (floatx4)0.0f;

    // staging (proven round 7): chunk swizzle pos = chunk ^ ((row>>1)&3)
    const int srow = t >> 2;
    const int skoff = (((t & 3) ^ ((t >> 3) & 3))) * 8;
    const size_t sldsOff = (size_t)t * 8;
    const int fkoff = (q ^ ((lc >> 1) & 3)) * 8;

    const ushort_t* pAh0 = hiA + (size_t)(n0 + srow) * FDIM + skoff;
    const ushort_t* pAh1 = hiA + (size_t)(n0 + srow + 64) * FDIM + skoff;
    const ushort_t* pBh0 = hiB + (size_t)(m0 + srow) * FDIM + skoff;
    const ushort_t* pBh1 = hiB + (size_t)(m0 + srow + 64) * FDIM + skoff;
    const ushort_t* pAl0 = loA + (size_t)(n0 + srow) * FDIM + skoff;
    const ushort_t* pAl1 = loA + (size_t)(n0 + srow + 64) * FDIM + skoff;
    const ushort_t* pBl0 = loB + (size_t)(m0 + srow) * FDIM + skoff;
    const ushort_t* pBl1 = loB + (size_t)(m0 + srow + 64) * FDIM + skoff;

    for (int k0 = 0; k0 < FDIM; k0 += BK) {
        if (k0) __syncthreads();
        GLDS(pAh0 + k0, Ah + sldsOff);
        GLDS(pAh1 + k0, Ah + 2048 + sldsOff);
        GLDS(pBh0 + k0, Bh + sldsOff);
        GLDS(pBh1 + k0, Bh + 2048 + sldsOff);
        GLDS(pAl0 + k0, Al + sldsOff);
        GLDS(pAl1 + k0, Al + 2048 + sldsOff);
        GLDS(pBl0 + k0, Bl + sldsOff);
        GLDS(pBl1 + k0, Bl + 2048 + sldsOff);
        __syncthreads();

        short8 ah[4], bh[4], al[4], bl[4];
#pragma unroll
        for (int i = 0; i < 4; i++) {
            int r = (wy * 64 + i * 16 + lc) * BK;
            ah[i] = *(const short8*)&Ah[r + fkoff];
            al[i] = *(const short8*)&Al[r + fkoff];
        }
#pragma unroll
        for (int j = 0; j < 4; j++) {
            int r = (wx * 64 + j * 16 + lc) * BK;
            bh[j] = *(const short8*)&Bh[r + fkoff];
            bl[j] = *(const short8*)&Bl[r + fkoff];
        }
#pragma unroll
        for (int i = 0; i < 4; i++)
#pragma unroll
            for (int j = 0; j < 4; j++) {
                acc[i][j] = __builtin_amdgcn_mfma_f32_16x16x32_bf16(ah[i], bh[j], acc[i][j], 0, 0, 0);
                acc[i][j] = __builtin_amdgcn_mfma_f32_16x16x32_bf16(ah[i], bl[j], acc[i][j], 0, 0, 0);
                acc[i][j] = __builtin_amdgcn_mfma_f32_16x16x32_bf16(al[i], bh[j], acc[i][j], 0, 0, 0);
            }
    }

    // ---- epilogue: C/D layout row = q*4+reg, col = lane&15 (verified) ----
    T2 colT[4];
#pragma unroll
    for (int j = 0; j < 4; j++) colT[j] = t2_sent();
    T2 rowT[4][4];

    const int cb = m0 + wx * 64 + lc;
#pragma unroll
    for (int i = 0; i < 4; i++) {
#pragma unroll
        for (int r = 0; r < 4; r++)
            rowT[i][r] = t2_make4(acc[i][0][r], acc[i][1][r], acc[i][2][r], acc[i][3][r],
                                  cb, cb + 16, cb + 32, cb + 48);
        const int rb = n0 + wy * 64 + i * 16 + q * 4;
#pragma unroll
        for (int j = 0; j < 4; j++)
            colT[j] = t2_merge(colT[j],
                t2_make4(acc[i][j][0], acc[i][j][1], acc[i][j][2], acc[i][j][3],
                         rb, rb + 1, rb + 2, rb + 3));
    }

    // cols: merge across the 4 quads (same column, different row-quarters)
#pragma unroll
    for (int j = 0; j < 4; j++) {
        colT[j] = t2_merge(colT[j], t2_shfl_xor(colT[j], 16));
        colT[j] = t2_merge(colT[j], t2_shfl_xor(colT[j], 32));
        if (q == 0) redC[(wx * 64 + j * 16 + lc) * 2 + wy] = t2_pack(colT[j]);
    }

    // rows: two LDS rounds (by wy), bank-spread slots, free 2-way access
#pragma unroll
    for (int round = 0; round < 2; round++) {
        __syncthreads();
        if (wy == round) {
#pragma unroll
            for (int i = 0; i < 4; i++)
#pragma unroll
                for (int r = 0; r < 4; r++) {
                    int row = i * 16 + q * 4 + r;                 // 0..63
                    int col = (lc << 1) | wx;                     // 0..31
                    int slot = row * 33 + ((col + row + 9 * q) & 31);
                    scrS1[slot] = rowT[i][r].s1;
                    scrS2[slot] = rowT[i][r].s2;
                    scrI[slot]  = rowT[i][r].i1;
                }
        }
        __syncthreads();
        {
            int row = t >> 2, chunk = t & 3;
            T2 a = t2_sent();
#pragma unroll
            for (int s = 0; s < 8; s++) {
                int slot = row * 33 + ((chunk << 3) | s);
                T2 b; b.s1 = scrS1[slot]; b.s2 = scrS2[slot]; b.i1 = scrI[slot];
                a = t2_merge(a, b);
            }
            a = t2_merge(a, t2_shfl_xor(a, 1));
            a = t2_merge(a, t2_shfl_xor(a, 2));
            if (chunk == 0)
                rowPart[(size_t)ctile * NPTS + n0 + round * 64 + row] = t2_pack(a);
        }
    }

    __syncthreads();
    if (t < 128) {
        T2 m = t2_unpack(redC[t * 2 + 0]);
        m = t2_merge(m, t2_unpack(redC[t * 2 + 1]));
        colPart[(size_t)rtile * MPTS + m0 + t] = t2_pack(m);
    }
}

// -------- fused final reduce (round-10 proven) --------
__global__ __launch_bounds__(256) void reduce_final(
    const float4* __restrict__ rowPart, const float4* __restrict__ colPart,
    float* __restrict__ out)
{
    __shared__ float4 sh[4][64];
    __shared__ int shFwd[64];
    __shared__ int shOk[64];
    const int t = threadIdx.x, nl = t & 63, sub = t >> 6;
    const int n = blockIdx.x * 64 + nl;

    T2 a = t2_sent();
#pragma unroll
    for (int k = 0; k < 16; k++)
        a = t2_merge(a, t2_unpack(rowPart[(size_t)(sub * 16 + k) * NPTS + n]));
    sh[sub][nl] = t2_pack(a);
    __syncthreads();
    if (t < 64) {
        T2 r = t2_unpack(sh[0][t]);
        r = t2_merge(r, t2_unpack(sh[1][t]));
        r = t2_merge(r, t2_unpack(sh[2][t]));
        r = t2_merge(r, t2_unpack(sh[3][t]));
        float c1 = fmaxf(1.0f - r.s1, 1e-6f), c2 = fmaxf(1.0f - r.s2, 1e-6f);
        float d1 = 1.414213f * sqrtf(c1), d2 = 1.414213f * sqrtf(c2);
        shFwd[t] = r.i1;
        shOk[t]  = ((d1 / d2) < 1.0f) ? 1 : 0;   // exact ref ratio test, RT=1.0
    }
    __syncthreads();
    const int fw = shFwd[nl];
    T2 c = t2_sent();
#pragma unroll
    for (int k = 0; k < 16; k++)
        c = t2_merge(c, t2_unpack(colPart[(size_t)(sub * 16 + k) * MPTS + fw]));
    sh[sub][nl] = t2_pack(c);
    __syncthreads();
    if (t < 64) {
        T2 r = t2_unpack(sh[0][t]);
        r = t2_merge(r, t2_unpack(sh[1][t]));
        r = t2_merge(r, t2_unpack(sh[2][t]));
        r = t2_merge(r, t2_unpack(sh[3][t]));
        float c1 = fmaxf(1.0f - r.s1, 1e-6f), c2 = fmaxf(1.0f - r.s2, 1e-6f);
        float d1 = 1.414213f * sqrtf(c1), d2 = 1.414213f * sqrtf(c2);
        bool bok = (d1 / d2) < 1.0f;
        int nn = blockIdx.x * 64 + t;
        bool mutual = (shOk[t] != 0) && bok && (r.i1 == nn);
        int idx0 = mutual ? shFwd[t] : -1;
        out[nn]             = (float)idx0;                // indices0
        out[NPTS + nn]      = -1.0f;                      // matches1 (all -1)
        out[2 * NPTS + nn]  = (idx0 > 0) ? 1.0f : 0.0f;   // mscores0 (strict >0 ref quirk)
        out[3 * NPTS + nn]  = 0.0f;                       // mscores1
    }
}

extern "C" void kernel_launch(void* const* d_in, const int* in_sizes, int n_in,
                              void* d_out, int out_size, void* d_ws, size_t ws_size,
                              hipStream_t stream)
{
    const float* d0 = (const float*)d_in[0];   // [1, 256, 8192] f32
    const float* d1 = (const float*)d_in[1];   // [1, 256, 8192] f32

    char* ws = (char*)d_ws;
    const size_t matB = (size_t)NPTS * FDIM * sizeof(ushort_t);      // 4 MB
    ushort_t* hiA = (ushort_t*)(ws);
    ushort_t* loA = (ushort_t*)(ws + matB);
    ushort_t* hiB = (ushort_t*)(ws + 2 * matB);
    ushort_t* loB = (ushort_t*)(ws + 3 * matB);
    char* p = ws + 4 * matB;
    const size_t rowBytes = (size_t)TCT * NPTS * sizeof(float4);     // 8 MB
    float4* rowPart = (float4*)p;
    float4* colPart = (float4*)(p + rowBytes);

    dim3 gt(NPTS / 64, FDIM / 64, 2);
    transpose_split<<<gt, 256, 0, stream>>>(d0, d1, hiA, loA, hiB, loB);

    dim3 g1(TCT, TRT);
    gemm_top2<<<g1, 256, 0, stream>>>(hiA, loA, hiB, loB, rowPart, colPart);
    reduce_final<<<NPTS / 64, 256, 0, stream>>>(rowPart, colPart, (float*)d_out);
}

// Round 13
// 180.344 us; speedup vs baseline: 1.0190x; 1.0065x over previous
//
#include <hip/hip_runtime.h>
#include <float.h>

#define NPTS 8192
#define MPTS 8192
#define FDIM 256

#define BM 128
#define BN 128
#define BK 64
#define TCT (MPTS / BN)   /* 64 column tiles */
#define TRT (NPTS / BM)   /* 64 row tiles */

typedef unsigned short ushort_t;
typedef unsigned int u32;
typedef __attribute__((ext_vector_type(8))) short short8;
typedef __attribute__((ext_vector_type(4))) float floatx4;

// ---- top-2-by-similarity (proven round 8): select on RAW s (max); clamp and
// sqrt applied only at the ratio test. Any orderings-could-differ case forces
// d1==d2 -> ratio==1 -> ok=false under RT=1.0 -> decisions unaffected.
struct T2 { float s1, s2; int i1; };   // s1 >= s2

__device__ __forceinline__ T2 t2_sent() { T2 a; a.s1 = -FLT_MAX; a.s2 = -FLT_MAX; a.i1 = 0; return a; }

__device__ __forceinline__ T2 t2_merge(T2 a, T2 b) {
    T2 r;
    r.s1 = fmaxf(a.s1, b.s1);
    r.i1 = (b.s1 > a.s1) ? b.i1 : a.i1;
    r.s2 = fmaxf(fminf(a.s1, b.s1), fmaxf(a.s2, b.s2));
    return r;
}
__device__ __forceinline__ T2 t2_make4(float v0, float v1, float v2, float v3,
                                       int i0, int i1_, int i2, int i3) {
    float lo01 = fminf(v0, v1), hi01 = fmaxf(v0, v1);
    float lo23 = fminf(v2, v3), hi23 = fmaxf(v2, v3);
    int a01 = (v1 > v0) ? i1_ : i0;
    int a23 = (v3 > v2) ? i3 : i2;
    T2 r;
    r.s1 = fmaxf(hi01, hi23);
    r.i1 = (hi23 > hi01) ? a23 : a01;
    r.s2 = fmaxf(fminf(hi01, hi23), fmaxf(lo01, lo23));
    return r;
}
__device__ __forceinline__ float4 t2_pack(T2 a) {
    return make_float4(a.s1, a.s2, __int_as_float(a.i1), 0.0f);
}
__device__ __forceinline__ T2 t2_unpack(float4 v) {
    T2 a; a.s1 = v.x; a.s2 = v.y; a.i1 = __float_as_int(v.z); return a;
}
__device__ __forceinline__ T2 t2_shfl_xor(T2 a, int m) {
    T2 r; r.s1 = __shfl_xor(a.s1, m); r.s2 = __shfl_xor(a.s2, m); r.i1 = __shfl_xor(a.i1, m);
    return r;
}

__device__ __forceinline__ float bf2f(ushort_t u) {
    union { u32 i; float f; } v; v.i = ((u32)u) << 16; return v.f;
}
__device__ __forceinline__ ushort_t f2bf_rtne(float x) {
    u32 u = __float_as_uint(x);
    u32 r = u + 0x7FFFu + ((u >> 16) & 1u);
    return (ushort_t)(r >> 16);
}

// -------- fused transpose + hi/lo split: float4 loads (16 B/lane) +
// proven conflict-free scalar LDS stores + u32-pair global stores --------
__global__ __launch_bounds__(256) void transpose_split(
    const float* __restrict__ s0, const float* __restrict__ s1,
    ushort_t* __restrict__ hi0, ushort_t* __restrict__ lo0,
    ushort_t* __restrict__ hi1, ushort_t* __restrict__ lo1)
{
    __shared__ ushort_t hiS[64][66];
    __shared__ ushort_t loS[64][66];
    const float* src = blockIdx.z ? s1 : s0;
    ushort_t* hiT = blockIdx.z ? hi1 : hi0;
    ushort_t* loT = blockIdx.z ? lo1 : lo0;
    const int t = threadIdx.x;
    const int n0 = blockIdx.x * 64, f0 = blockIdx.y * 64;

#pragma unroll
    for (int p = 0; p < 4; p++) {
        int fl = (t >> 4) + p * 16;          // feature row 0..63
        int nl = (t & 15) * 4;               // 4 consecutive points
        float4 x = *(const float4*)&src[(size_t)(f0 + fl) * NPTS + n0 + nl];
        float xs[4] = {x.x, x.y, x.z, x.w};
#pragma unroll
        for (int e = 0; e < 4; e++) {
            ushort_t hb = f2bf_rtne(xs[e]);
            ushort_t lb = f2bf_rtne(xs[e] - bf2f(hb));
            hiS[nl + e][fl] = hb;            // 66-stride: 2-way banks (free)
            loS[nl + e][fl] = lb;
        }
    }
    __syncthreads();
#pragma unroll
    for (int p = 0; p < 8; p++) {
        int nl = (t >> 5) + p * 8;
        int fp = (t & 31) * 2;
        u32 hw = (u32)hiS[nl][fp] | ((u32)hiS[nl][fp + 1] << 16);
        u32 lw = (u32)loS[nl][fp] | ((u32)loS[nl][fp + 1] << 16);
        size_t o = (size_t)(n0 + nl) * FDIM + f0 + fp;
        *(u32*)&hiT[o] = hw;
        *(u32*)&loT[o] = lw;
    }
}

#define GLDS(g, l) __builtin_amdgcn_global_load_lds( \
    (const __attribute__((address_space(1))) void*)(g), \
    (__attribute__((address_space(3))) void*)(l), 16, 0, 0)

// -------- fused MFMA GEMM (16x16x32, BK=64: half the barriers) + top-2 ----
// LDS per array: 128 rows x 64 k (128 B rows, 8 x 16B chunks). Chunk swizzle:
// global chunk g stored at pos = g ^ (row&7); fragment for (k-half s, quad q)
// reads pos (s*4+q) ^ (row&7). Both staging (contiguous lane x 16B dest,
// GLDS-legal) and fragment reads land as uniform 2-way bank access (free).
__global__ __launch_bounds__(256, 2) void gemm_top2(
    const ushort_t* __restrict__ hiA, const ushort_t* __restrict__ loA,
    const ushort_t* __restrict__ hiB, const ushort_t* __restrict__ loB,
    float4* __restrict__ rowPart, float4* __restrict__ colPart)
{
    __shared__ char smem[65536];
    ushort_t* Ah = (ushort_t*)smem;                 // 16 KB each (staging)
    ushort_t* Bh = (ushort_t*)(smem + 16384);
    ushort_t* Al = (ushort_t*)(smem + 32768);
    ushort_t* Bl = (ushort_t*)(smem + 49152);
    // epilogue aliases (staging dead after K-loop + barrier):
    float* scrS1 = (float*)smem;                    // 64*33*4 = 8448 B
    float* scrS2 = (float*)(smem + 8448);
    int*   scrI  = (int*)(smem + 16896);            // ends 25344
    float4* redC = (float4*)(smem + 25600);         // 128*2*16 = 4096 B

    const int t = threadIdx.x;
    const int lane = t & 63, lc = lane & 15, q = lane >> 4;
    const int w = t >> 6, wx = w & 1, wy = w >> 1;
    const int ctile = blockIdx.x, rtile = blockIdx.y;
    const int n0 = rtile * BM, m0 = ctile * BN;

    floatx4 acc[4][4];
#pragma unroll
    for (int i = 0; i < 4; i++)
#pragma unroll
        for (int j = 0; j < 4; j++) acc[i][j] = (floatx4)0.0f;

    // staging map: chunk L = cc*256 + t -> row = L>>3, pos = L&7,
    // global chunk g = pos ^ (row&7); LDS dest = L*16 B (lane-contiguous).
    int srcOff[4];   // (row*FDIM + g*8), k0 added per iter
#pragma unroll
    for (int cc = 0; cc < 4; cc++) {
        int L = cc * 256 + t;
        int row = L >> 3;
        int g = (L & 7) ^ (row & 7);
        srcOff[cc] = row * FDIM + g * 8;
    }
    const ushort_t* bAh = hiA + (size_t)n0 * FDIM;
    const ushort_t* bAl = loA + (size_t)n0 * FDIM;
    const ushort_t* bBh = hiB + (size_t)m0 * FDIM;
    const ushort_t* bBl = loB + (size_t)m0 * FDIM;

    // fragment offsets (ushort units): row*64 + ((s*4+q)^(row&7))*8
    int aoff[4][2], boff[4][2];
#pragma unroll
    for (int i = 0; i < 4; i++) {
        int ra = wy * 64 + i * 16 + lc;
        int rb = wx * 64 + i * 16 + lc;
#pragma unroll
        for (int s = 0; s < 2; s++) {
            aoff[i][s] = ra * BK + (((s * 4 + q) ^ (ra & 7)) * 8);
            boff[i][s] = rb * BK + (((s * 4 + q) ^ (rb & 7)) * 8);
        }
    }

    for (int k0 = 0; k0 < FDIM; k0 += BK) {
        if (k0) __syncthreads();
#pragma unroll
        for (int cc = 0; cc < 4; cc++) {
            int so = srcOff[cc] + k0;
            int ld = (cc * 256 + t) * 8;
            GLDS(bAh + so, Ah + ld);
            GLDS(bBh + so, Bh + ld);
            GLDS(bAl + so, Al + ld);
            GLDS(bBl + so, Bl + ld);
        }
        __syncthreads();

#pragma unroll
        for (int s = 0; s < 2; s++) {
            short8 ah[4], bh[4], al[4], bl[4];
#pragma unroll
            for (int i = 0; i < 4; i++) {
                ah[i] = *(const short8*)&Ah[aoff[i][s]];
                al[i] = *(const short8*)&Al[aoff[i][s]];
            }
#pragma unroll
            for (int j = 0; j < 4; j++) {
                bh[j] = *(const short8*)&Bh[boff[j][s]];
                bl[j] = *(const short8*)&Bl[boff[j][s]];
            }
#pragma unroll
            for (int i = 0; i < 4; i++)
#pragma unroll
                for (int j = 0; j < 4; j++) {
                    acc[i][j] = __builtin_amdgcn_mfma_f32_16x16x32_bf16(ah[i], bh[j], acc[i][j], 0, 0, 0);
                    acc[i][j] = __builtin_amdgcn_mfma_f32_16x16x32_bf16(ah[i], bl[j], acc[i][j], 0, 0, 0);
                    acc[i][j] = __builtin_amdgcn_mfma_f32_16x16x32_bf16(al[i], bh[j], acc[i][j], 0, 0, 0);
                }
        }
    }

    // ---- epilogue: C/D layout row = q*4+reg, col = lane&15 (verified) ----
    T2 colT[4];
#pragma unroll
    for (int j = 0; j < 4; j++) colT[j] = t2_sent();
    T2 rowT[4][4];

    const int cb = m0 + wx * 64 + lc;
#pragma unroll
    for (int i = 0; i < 4; i++) {
#pragma unroll
        for (int r = 0; r < 4; r++)
            rowT[i][r] = t2_make4(acc[i][0][r], acc[i][1][r], acc[i][2][r], acc[i][3][r],
                                  cb, cb + 16, cb + 32, cb + 48);
        const int rb = n0 + wy * 64 + i * 16 + q * 4;
#pragma unroll
        for (int j = 0; j < 4; j++)
            colT[j] = t2_merge(colT[j],
                t2_make4(acc[i][j][0], acc[i][j][1], acc[i][j][2], acc[i][j][3],
                         rb, rb + 1, rb + 2, rb + 3));
    }

    // cols: merge across the 4 quads (same column, different row-quarters)
#pragma unroll
    for (int j = 0; j < 4; j++) {
        colT[j] = t2_merge(colT[j], t2_shfl_xor(colT[j], 16));
        colT[j] = t2_merge(colT[j], t2_shfl_xor(colT[j], 32));
        if (q == 0) redC[(wx * 64 + j * 16 + lc) * 2 + wy] = t2_pack(colT[j]);
    }

    // rows: two LDS rounds (by wy), bank-spread slots, free 2-way access
#pragma unroll
    for (int round = 0; round < 2; round++) {
        __syncthreads();
        if (wy == round) {
#pragma unroll
            for (int i = 0; i < 4; i++)
#pragma unroll
                for (int r = 0; r < 4; r++) {
                    int row = i * 16 + q * 4 + r;                 // 0..63
                    int col = (lc << 1) | wx;                     // 0..31
                    int slot = row * 33 + ((col + row + 9 * q) & 31);
                    scrS1[slot] = rowT[i][r].s1;
                    scrS2[slot] = rowT[i][r].s2;
                    scrI[slot]  = rowT[i][r].i1;
                }
        }
        __syncthreads();
        {
            int row = t >> 2, chunk = t & 3;
            T2 a = t2_sent();
#pragma unroll
            for (int s = 0; s < 8; s++) {
                int slot = row * 33 + ((chunk << 3) | s);
                T2 b; b.s1 = scrS1[slot]; b.s2 = scrS2[slot]; b.i1 = scrI[slot];
                a = t2_merge(a, b);
            }
            a = t2_merge(a, t2_shfl_xor(a, 1));
            a = t2_merge(a, t2_shfl_xor(a, 2));
            if (chunk == 0)
                rowPart[(size_t)ctile * NPTS + n0 + round * 64 + row] = t2_pack(a);
        }
    }

    __syncthreads();
    if (t < 128) {
        T2 m = t2_unpack(redC[t * 2 + 0]);
        m = t2_merge(m, t2_unpack(redC[t * 2 + 1]));
        colPart[(size_t)rtile * MPTS + m0 + t] = t2_pack(m);
    }
}

// -------- fused final reduce (round-10 proven) --------
__global__ __launch_bounds__(256) void reduce_final(
    const float4* __restrict__ rowPart, const float4* __restrict__ colPart,
    float* __restrict__ out)
{
    __shared__ float4 sh[4][64];
    __shared__ int shFwd[64];
    __shared__ int shOk[64];
    const int t = threadIdx.x, nl = t & 63, sub = t >> 6;
    const int n = blockIdx.x * 64 + nl;

    T2 a = t2_sent();
#pragma unroll
    for (int k = 0; k < 16; k++)
        a = t2_merge(a, t2_unpack(rowPart[(size_t)(sub * 16 + k) * NPTS + n]));
    sh[sub][nl] = t2_pack(a);
    __syncthreads();
    if (t < 64) {
        T2 r = t2_unpack(sh[0][t]);
        r = t2_merge(r, t2_unpack(sh[1][t]));
        r = t2_merge(r, t2_unpack(sh[2][t]));
        r = t2_merge(r, t2_unpack(sh[3][t]));
        float c1 = fmaxf(1.0f - r.s1, 1e-6f), c2 = fmaxf(1.0f - r.s2, 1e-6f);
        float d1 = 1.414213f * sqrtf(c1), d2 = 1.414213f * sqrtf(c2);
        shFwd[t] = r.i1;
        shOk[t]  = ((d1 / d2) < 1.0f) ? 1 : 0;   // exact ref ratio test, RT=1.0
    }
    __syncthreads();
    const int fw = shFwd[nl];
    T2 c = t2_sent();
#pragma unroll
    for (int k = 0; k < 16; k++)
        c = t2_merge(c, t2_unpack(colPart[(size_t)(sub * 16 + k) * MPTS + fw]));
    sh[sub][nl] = t2_pack(c);
    __syncthreads();
    if (t < 64) {
        T2 r = t2_unpack(sh[0][t]);
        r = t2_merge(r, t2_unpack(sh[1][t]));
        r = t2_merge(r, t2_unpack(sh[2][t]));
        r = t2_merge(r, t2_unpack(sh[3][t]));
        float c1 = fmaxf(1.0f - r.s1, 1e-6f), c2 = fmaxf(1.0f - r.s2, 1e-6f);
        float d1 = 1.414213f * sqrtf(c1), d2 = 1.414213f * sqrtf(c2);
        bool bok = (d1 / d2) < 1.0f;
        int nn = blockIdx.x * 64 + t;
        bool mutual = (shOk[t] != 0) && bok && (r.i1 == nn);
        int idx0 = mutual ? shFwd[t] : -1;
        out[nn]             = (float)idx0;                // indices0
        out[NPTS + nn]      = -1.0f;                      // matches1 (all -1)
        out[2 * NPTS + nn]  = (idx0 > 0) ? 1.0f : 0.0f;   // mscores0 (strict >0 ref quirk)
        out[3 * NPTS + nn]  = 0.0f;                       // mscores1
    }
}

extern "C" void kernel_launch(void* const* d_in, const int* in_sizes, int n_in,
                              void* d_out, int out_size, void* d_ws, size_t ws_size,
                              hipStream_t stream)
{
    const float* d0 = (const float*)d_in[0];   // [1, 256, 8192] f32
    const float* d1 = (const float*)d_in[1];   // [1, 256, 8192] f32

    char* ws = (char*)d_ws;
    const size_t matB = (size_t)NPTS * FDIM * sizeof(ushort_t);      // 4 MB
    ushort_t* hiA = (ushort_t*)(ws);
    ushort_t* loA = (ushort_t*)(ws + matB);
    ushort_t* hiB = (ushort_t*)(ws + 2 * matB);
    ushort_t* loB = (ushort_t*)(ws + 3 * matB);
    char* p = ws + 4 * matB;
    const size_t rowBytes = (size_t)TCT * NPTS * sizeof(float4);     // 8 MB
    float4* rowPart = (float4*)p;
    float4* colPart = (float4*)(p + rowBytes);

    dim3 gt(NPTS / 64, FDIM / 64, 2);
    transpose_split<<<gt, 256, 0, stream>>>(d0, d1, hiA, loA, hiB, loB);

    dim3 g1(TCT, TRT);
    gemm_top2<<<g1, 256, 0, stream>>>(hiA, loA, hiB, loB, rowPart, colPart);
    reduce_final<<<NPTS / 64, 256, 0, stream>>>(rowPart, colPart, (float*)d_out);
}